// Round 7
// baseline (1044.035 us; speedup 1.0000x reference)
//
#include <hip/hip_runtime.h>
#include <hip/hip_bf16.h>
#include <hip/hip_cooperative_groups.h>

// DomainEncoder: 8-expert MoE MLP, N=32768, 256 -> 1024 (LN+ReLU) -> 256.
// Round-7 vs round-6 (340 us: prep cooperative kernel was launched with 256
// blocks = 1 wave/SIMD -> 130 us latency-bound disaster):
//   - prep: 2048 blocks (8/CU, co-residency structurally guaranteed by
//     __launch_bounds__(256,8): 24 VGPR < 64 cap, 4.6KB LDS x8 < 160KB).
//     All phases grid-stride. Transpose back to 2 jobs/block parallelism.
//   - gemm_a, gemm_b64 byte-identical to round-6 (correctness-validated).

namespace cg = cooperative_groups;

#define ND 8
#define NROWS 32768
#define DIN 256
#define DHID 1024
#define DOUT 256
#define MPAD 33792          // 32768 + 8*128 worst-case padding
#define NTILES 264          // 256 + 8 worst-case row tiles (264 = 8*33)
#define PREPB 2048          // prep grid: 8 blocks/CU co-resident

typedef short short8 __attribute__((ext_vector_type(8)));
typedef float floatx4 __attribute__((ext_vector_type(4)));

__device__ __forceinline__ unsigned short f2bf(float f) {
    unsigned u = __builtin_bit_cast(unsigned, f);
    unsigned r = u + 0x7fff + ((u >> 16) & 1);   // RNE (inputs finite)
    return (unsigned short)(r >> 16);
}
__device__ __forceinline__ float bf2f(unsigned short h) {
    unsigned u = ((unsigned)h) << 16;
    return __builtin_bit_cast(float, u);
}

#define GLDS16(gp, lp) __builtin_amdgcn_global_load_lds( \
    (const __attribute__((address_space(1))) void*)(gp), \
    (__attribute__((address_space(3))) void*)(lp), 16, 0, 0)

// ---------------- 0. cooperative prep: everything before the GEMMs -----------
// 2048 blocks x 256 threads (8 blocks/CU guaranteed co-resident).
// P0: CNT zero + perm init + both weight transposes (grid-stride 4096 tiles;
//     W2T written with slot^=row&7 content swizzle within 128B k-groups)
// P1: domain histogram   P2: tile metadata + cursors   P3: position assign
// P4: gather-copy x -> XS (sorted, bf16)
__global__ __launch_bounds__(256, 8)
void prep(const float* __restrict__ W1, unsigned short* __restrict__ W1T,
          const float* __restrict__ W2, unsigned short* __restrict__ W2T,
          const int* __restrict__ dt, const float* __restrict__ x,
          unsigned short* __restrict__ XS, int* __restrict__ perm,
          int* __restrict__ pos, int* __restrict__ cnt,
          int2* __restrict__ meta) {
    cg::grid_group grid = cg::this_grid();
    __shared__ float t[32][33];
    __shared__ int lc[ND], lb[ND];
    __shared__ int base[ND], ntc[ND];
    const int tid = threadIdx.x;
    const int bid = blockIdx.x;
    const int nb = gridDim.x;

    // ---- P0: cnt zero + perm init + transposes (grid-stride) ----
    if (bid == 0 && tid < 16) cnt[tid] = 0;
    for (int i = bid * 256 + tid; i < MPAD; i += nb * 256) perm[i] = -1;
    const int tx = tid & 31, ty = tid >> 5;      // 32x8 transpose layout
    for (int job = bid; job < 4096; job += nb) {
        const float* in; unsigned short* out; int R, C, bx, by, z, is2;
        if (job < 2048) { in = W1; out = W1T; R = DIN;  C = DHID; is2 = 0;
                          bx = job & 31; by = (job >> 5) & 7;  z = job >> 8; }
        else { const int j2 = job - 2048;
               in = W2; out = W2T; R = DHID; C = DOUT; is2 = 1;
               bx = j2 & 7;  by = (j2 >> 3) & 31; z = j2 >> 8; }
        const int c0 = bx * 32, r0 = by * 32;
        const float* src = in + (size_t)z * R * C;
        unsigned short* dst = out + (size_t)z * R * C;
#pragma unroll
        for (int i = 0; i < 32; i += 8)
            t[ty + i][tx] = src[(size_t)(r0 + ty + i) * C + c0 + tx];
        __syncthreads();
#pragma unroll
        for (int i = 0; i < 32; i += 8) {
            const int row = c0 + ty + i;          // output row (N-dim)
            int k = r0 + tx;                      // output col (K-dim)
            if (is2)                              // content swizzle for BK=64 LDS
                k = (k & ~0x38) | (((((k >> 3) & 7) ^ (row & 7))) << 3);
            dst[(size_t)row * R + k] = f2bf(t[tx][ty + i]);
        }
        __syncthreads();
    }
    grid.sync();

    // ---- P1: histogram (128 chunks of 256 rows, grid-stride) ----
    for (int chunk = bid; chunk < 128; chunk += nb) {
        if (tid < ND) lc[tid] = 0;
        __syncthreads();
        atomicAdd(&lc[dt[chunk * 256 + tid]], 1);
        __syncthreads();
        if (tid < ND && lc[tid] > 0) atomicAdd(&cnt[tid], lc[tid]);
        __syncthreads();
    }
    grid.sync();

    // ---- P2: meta + cursors (block 0) ----
    if (bid == 0) {
        if (tid == 0) {
            int off = 0;
            for (int d = 0; d < ND; d++) {
                base[d] = off;
                ntc[d] = (cnt[d] + 127) >> 7;
                cnt[8 + d] = off;                 // cursors
                off += ntc[d] << 7;
            }
        }
        __syncthreads();
        for (int i = tid; i < NTILES; i += 256) {
            int2 m = make_int2(-1, 0);
#pragma unroll
            for (int d = 0; d < ND; d++) {
                const int ti = i - (base[d] >> 7);
                if (ti >= 0 && ti < ntc[d]) m = make_int2(d, base[d] + (ti << 7));
            }
            meta[i] = m;
        }
    }
    grid.sync();

    // ---- P3: position assignment (128 chunks, grid-stride) ----
    for (int chunk = bid; chunk < 128; chunk += nb) {
        if (tid < ND) lc[tid] = 0;
        __syncthreads();
        const int r = chunk * 256 + tid;
        const int d = dt[r];
        const int myrank = atomicAdd(&lc[d], 1);
        __syncthreads();
        if (tid < ND && lc[tid] > 0)
            lb[tid] = atomicAdd(&cnt[8 + tid], lc[tid]);
        __syncthreads();
        const int p = lb[d] + myrank;
        pos[r] = p;
        perm[p] = r;
        __syncthreads();
    }
    grid.sync();

    // ---- P4: gather-copy x -> XS (2M 16B-chunks, grid-stride) ----
    for (int idx = bid * 256 + tid; idx < NROWS * 64; idx += nb * 256) {
        const int row = idx >> 6, c = idx & 63;
        const int p = pos[row];
        const float4 v = ((const float4*)(x + (size_t)row * DIN))[c];
        ushort4 o;
        o.x = f2bf(v.x); o.y = f2bf(v.y); o.z = f2bf(v.z); o.w = f2bf(v.w);
        ((ushort4*)(XS + (size_t)p * DIN))[c] = o;
    }
}

// ---------------- 1. GEMM-A: H = XS @ W1^T + b1, LN partials ------------------
// 128x128 tile, 4 waves 2x2, BK=32, dbuf single-barrier (round-5 structure).
__global__ __launch_bounds__(256, 2)
void gemm_a(const unsigned short* __restrict__ A,
            const unsigned short* __restrict__ Bt,
            const float* __restrict__ bias,
            const int2* __restrict__ meta,
            unsigned short* __restrict__ Cbf,
            float2* __restrict__ spart) {
    constexpr int K = DIN, Ntot = DHID, NB = 8, NWG = NTILES * NB, NS = K / 32;
    const int bid = (int)blockIdx.x;
    const int wid = (bid & 7) * (NWG >> 3) + (bid >> 3);
    const int tile = wid / NB;
    const int n0 = (wid % NB) * 128;
    const int2 md = meta[tile];
    const int dom = md.x;
    if (dom < 0) return;
    const int m0 = md.y;

    __shared__ unsigned short As[2][128 * 32];
    __shared__ unsigned short Bs[2][128 * 32];
    __shared__ float sred[2][128];

    const int tid = threadIdx.x;
    const int lane = tid & 63;
    const int w = tid >> 6;
    const int wr = w >> 1, wc = w & 1;
    const int l15 = lane & 15;

    const unsigned short* Abase = A + (size_t)m0 * K;
    const unsigned short* Bbase = Bt + (size_t)dom * Ntot * K + (size_t)n0 * K;

    if (tid < 128) { sred[0][tid] = 0.f; sred[1][tid] = 0.f; }

#define STAGE_AB(buf, t_) {                                                    \
        const int k0_ = (t_) * 32;                                             \
        _Pragma("unroll")                                                      \
        for (int it = 0; it < 2; ++it) {                                       \
            const int c = w * 128 + it * 64 + lane;                            \
            const int m_ = c >> 2, kcc = c & 3;                                \
            GLDS16(Bbase + (size_t)m_ * K + k0_ + kcc * 8,                     \
                   &Bs[buf][(w * 128 + it * 64) * 8]);                         \
            GLDS16(Abase + (size_t)m_ * K + k0_ + kcc * 8,                     \
                   &As[buf][(w * 128 + it * 64) * 8]);                         \
        }                                                                      \
    }

    floatx4 acc[4][4];
#pragma unroll
    for (int i = 0; i < 4; i++)
#pragma unroll
        for (int j = 0; j < 4; j++) acc[i][j] = 0.f;

    STAGE_AB(0, 0)
    __syncthreads();

    int cur = 0;
    const int kk = (lane >> 4) * 8;
    for (int t = 0; t < NS - 1; ++t) {
        const int nx = cur ^ 1;
        STAGE_AB(nx, t + 1)
        short8 a[4], b[4];
#pragma unroll
        for (int i = 0; i < 4; i++) {
            const int m = wr * 64 + i * 16 + l15;
            a[i] = *(const short8*)&As[cur][m * 32 + kk];
            const int n = wc * 64 + i * 16 + l15;
            b[i] = *(const short8*)&Bs[cur][n * 32 + kk];
        }
        __builtin_amdgcn_s_setprio(1);
#pragma unroll
        for (int i = 0; i < 4; i++)
#pragma unroll
            for (int j = 0; j < 4; j++)
                acc[i][j] = __builtin_amdgcn_mfma_f32_16x16x32_bf16(a[i], b[j], acc[i][j], 0, 0, 0);
        __builtin_amdgcn_s_setprio(0);
        __syncthreads();
        cur = nx;
    }
    {
        short8 a[4], b[4];
#pragma unroll
        for (int i = 0; i < 4; i++) {
            const int m = wr * 64 + i * 16 + l15;
            a[i] = *(const short8*)&As[cur][m * 32 + kk];
            const int n = wc * 64 + i * 16 + l15;
            b[i] = *(const short8*)&Bs[cur][n * 32 + kk];
        }
        __builtin_amdgcn_s_setprio(1);
#pragma unroll
        for (int i = 0; i < 4; i++)
#pragma unroll
            for (int j = 0; j < 4; j++)
                acc[i][j] = __builtin_amdgcn_mfma_f32_16x16x32_bf16(a[i], b[j], acc[i][j], 0, 0, 0);
        __builtin_amdgcn_s_setprio(0);
    }
#undef STAGE_AB

    // epilogue: write H = h+b1 (bf16) + per-row LN partials
    const int quad = lane >> 4;
    float bv[4];
#pragma unroll
    for (int j = 0; j < 4; j++)
        bv[j] = bias[dom * Ntot + n0 + wc * 64 + j * 16 + l15];
#pragma unroll
    for (int i = 0; i < 4; i++) {
#pragma unroll
        for (int r = 0; r < 4; r++) {
            const int rl = wr * 64 + i * 16 + quad * 4 + r;
            float s = 0.f, s2 = 0.f;
#pragma unroll
            for (int j = 0; j < 4; j++) {
                const float v = acc[i][j][r] + bv[j];
                Cbf[(size_t)(m0 + rl) * Ntot + n0 + wc * 64 + j * 16 + l15] = f2bf(v);
                s += v; s2 += v * v;
            }
#pragma unroll
            for (int o = 8; o; o >>= 1) {
                s  += __shfl_xor(s, o, 64);
                s2 += __shfl_xor(s2, o, 64);
            }
            if (l15 == 0) {
                atomicAdd(&sred[0][rl], s);
                atomicAdd(&sred[1][rl], s2);
            }
        }
    }
    __syncthreads();
    if (tid < 128)
        spart[(size_t)(n0 >> 7) * MPAD + m0 + tid] =
            make_float2(sred[0][tid], sred[1][tid]);
}

// ---------------- 2. GEMM-B: out = LN_ReLU(H) @ W2^T + b2, BK=64 --------------
// 128x128 tile, 4 waves 2x2, 16 K-steps, T2 XOR-swizzled LDS (A reg-staged,
// B linear GLDS from pre-swizzled W2T), scatter fp32 out via perm.
__global__ __launch_bounds__(256, 2)
void gemm_b64(const unsigned short* __restrict__ H,
              const unsigned short* __restrict__ W2T,
              const float* __restrict__ b2,
              const int2* __restrict__ meta,
              const int* __restrict__ perm,
              float* __restrict__ out,
              const float2* __restrict__ spart,
              const float* __restrict__ gamma,
              const float* __restrict__ beta) {
    constexpr int K = DHID, NWG = NTILES * 2, NS = K / 64;
    const int bid = (int)blockIdx.x;
    const int wid = (bid & 7) * (NWG >> 3) + (bid >> 3);
    const int tile = wid >> 1;
    const int n0 = (wid & 1) * 128;
    const int2 md = meta[tile];
    const int dom = md.x;
    if (dom < 0) return;
    const int m0 = md.y;

    __shared__ unsigned short As[2][128 * 64];   // 2 x 16 KB
    __shared__ unsigned short Bs[2][128 * 64];   // 2 x 16 KB
    __shared__ float gb[2048];                   // gamma[1024] beta[1024]

    const int tid = threadIdx.x;
    const int lane = tid & 63;
    const int w = tid >> 6;
    const int wr = w >> 1, wc = w & 1;
    const int l15 = lane & 15;
    const int quad = lane >> 4;

    const unsigned short* Hbase = H + (size_t)m0 * K;
    const unsigned short* Bbase = W2T + (size_t)dom * DOUT * K + (size_t)n0 * K;

    // gamma/beta -> LDS
    ((float4*)gb)[tid] = ((const float4*)(gamma + dom * DHID))[tid];
    ((float4*)(gb + 1024))[tid] = ((const float4*)(beta + dom * DHID))[tid];

    const int ma = w * 32 + (lane >> 2);   // staged rows: ma, ma+16
    const int kc = lane & 3;               // staged slots: kc, kc+4 (of 8)
    float muv[2], rsv[2];
#pragma unroll
    for (int h2 = 0; h2 < 2; ++h2) {
        const int rm = m0 + ma + h2 * 16;
        float s = 0.f, s2 = 0.f;
#pragma unroll
        for (int nb = 0; nb < 8; ++nb) {
            const float2 p = spart[(size_t)nb * MPAD + rm];
            s += p.x; s2 += p.y;
        }
        const float mu = s * (1.f / 1024.f);
        const float var = fmaxf(s2 * (1.f / 1024.f) - mu * mu, 0.f);
        muv[h2] = mu;
        rsv[h2] = rsqrtf(var + 1e-5f);
    }

    short8 hv[2][2];   // [row-half][slot-half], literal-indexed only

#define LOAD_H(t_) {                                                           \
        hv[0][0] = *(const short8*)(Hbase + (size_t)ma * K + (t_) * 64 + kc * 8);        \
        hv[0][1] = *(const short8*)(Hbase + (size_t)ma * K + (t_) * 64 + (kc + 4) * 8);  \
        hv[1][0] = *(const short8*)(Hbase + (size_t)(ma + 16) * K + (t_) * 64 + kc * 8); \
        hv[1][1] = *(const short8*)(Hbase + (size_t)(ma + 16) * K + (t_) * 64 + (kc + 4) * 8); }

#define XFRM(buf, t_) {                                                        \
        _Pragma("unroll")                                                      \
        for (int r2 = 0; r2 < 2; ++r2) {                                       \
            const int row = ma + r2 * 16;                                      \
            const float mu = muv[r2], rs = rsv[r2];                            \
            _Pragma("unroll")                                                  \
            for (int c2 = 0; c2 < 2; ++c2) {                                   \
                const int s_ = kc + c2 * 4;                                    \
                const int k1 = (t_) * 64 + s_ * 8;                             \
                const float4 g0 = *(const float4*)&gb[k1];                     \
                const float4 g1 = *(const float4*)&gb[k1 + 4];                 \
                const float4 e0 = *(const float4*)&gb[1024 + k1];              \
                const float4 e1 = *(const float4*)&gb[1024 + k1 + 4];          \
                const float gA[8] = {g0.x, g0.y, g0.z, g0.w,                   \
                                     g1.x, g1.y, g1.z, g1.w};                  \
                const float eA[8] = {e0.x, e0.y, e0.z, e0.w,                   \
                                     e1.x, e1.y, e1.z, e1.w};                  \
                const short8 hvv = hv[r2][c2];                                 \
                short8 o;                                                      \
                _Pragma("unroll")                                              \
                for (int e = 0; e < 8; ++e) {                                  \
                    const float rg = gA[e] * rs;                               \
                    const float v = fmaxf(fmaf(bf2f((unsigned short)hvv[e]),   \
                                   rg, fmaf(-mu, rg, eA[e])), 0.f);            \
                    o[e] = (short)f2bf(v);                                     \
                }                                                              \
                *(short8*)&As[buf][row * 64 + ((s_ ^ (row & 7)) << 3)] = o;    \
            }                                                                  \
        }                                                                      \
    }

#define STAGE_B(buf, t_) {                                                     \
        _Pragma("unroll")                                                      \
        for (int it = 0; it < 4; ++it) {                                       \
            const int cb = w * 256 + it * 64;                                  \
            const int c = cb + lane;                                           \
            const int m_ = c >> 3, j_ = c & 7;                                 \
            GLDS16(Bbase + (size_t)m_ * K + (t_) * 64 + j_ * 8,                \
                   &Bs[buf][cb * 8]);                                          \
        }                                                                      \
    }

#define COMPUTE(buf) {                                                         \
        _Pragma("unroll")                                                      \
        for (int h = 0; h < 2; ++h) {                                          \
            short8 a[4], b[4];                                                 \
            _Pragma("unroll")                                                  \
            for (int i = 0; i < 4; ++i) {                                      \
                const int m = wr * 64 + i * 16 + l15;                          \
                a[i] = *(const short8*)&As[buf][m * 64 +                       \
                        (((h * 4 + quad) ^ (m & 7)) << 3)];                    \
                const int n = wc * 64 + i * 16 + l15;                          \
                b[i] = *(const short8*)&Bs[buf][n * 64 +                       \
                        (((h * 4 + quad) ^ (n & 7)) << 3)];                    \
            }                                                                  \
            __builtin_amdgcn_s_setprio(1);                                     \
            _Pragma("unroll")                                                  \
            for (int i = 0; i < 4; ++i)                                        \
                _Pragma("unroll")                                              \
                for (int j = 0; j < 4; ++j)                                    \
                    acc[i][j] = __builtin_amdgcn_mfma_f32_16x16x32_bf16(       \
                        a[i], b[j], acc[i][j], 0, 0, 0);                       \
            __builtin_amdgcn_s_setprio(0);                                     \
        }                                                                      \
    }

    floatx4 acc[4][4];
#pragma unroll
    for (int i = 0; i < 4; i++)
#pragma unroll
        for (int j = 0; j < 4; j++) acc[i][j] = 0.f;

    // prologue
    STAGE_B(0, 0)          // fire-and-forget, earliest flight
    LOAD_H(0)
    __syncthreads();       // gb visible to all waves
    XFRM(0, 0)
    LOAD_H(1)
    __syncthreads();       // As[0] ds_writes + Bs[0] GLDS drained

    int cur = 0;
    for (int t = 0; t < NS - 1; ++t) {
        const int nx = cur ^ 1;
        STAGE_B(nx, t + 1)
        XFRM(nx, t + 1)                 // uses H(t+1) regs
        if (t + 2 < NS) LOAD_H(t + 2)   // flight = rest of this step
        COMPUTE(cur)
        __syncthreads();
        cur = nx;
    }
    COMPUTE(cur)

#undef LOAD_H
#undef XFRM
#undef STAGE_B
#undef COMPUTE

    // epilogue: scatter out = acc + b2 via perm (padding rows skipped)
    float bv[4];
#pragma unroll
    for (int j = 0; j < 4; j++)
        bv[j] = b2[dom * DOUT + n0 + wc * 64 + j * 16 + l15];
#pragma unroll
    for (int i = 0; i < 4; i++) {
        const int rowbase = m0 + wr * 64 + i * 16 + quad * 4;
#pragma unroll
        for (int r = 0; r < 4; r++) {
            const int orig = perm[rowbase + r];
            if (orig < 0) continue;
#pragma unroll
            for (int j = 0; j < 4; j++) {
                const int col = n0 + wc * 64 + j * 16 + l15;
                out[(size_t)orig * DOUT + col] = acc[i][j][r] + bv[j];
            }
        }
    }
}

// ---------------- launch ------------------------------------------------------
extern "C" void kernel_launch(void* const* d_in, const int* in_sizes, int n_in,
                              void* d_out, int out_size, void* d_ws, size_t ws_size,
                              hipStream_t stream) {
    const float* x = (const float*)d_in[0];
    const int* dt = (const int*)d_in[1];
    const float* W1 = (const float*)d_in[2];
    const float* b1 = (const float*)d_in[3];
    const float* gamma = (const float*)d_in[4];
    const float* beta = (const float*)d_in[5];
    const float* W2 = (const float*)d_in[6];
    const float* b2 = (const float*)d_in[7];
    float* out = (float*)d_out;

    char* ws = (char*)d_ws;
    size_t off = 0;
    auto take = [&](size_t nbytes) -> char* {
        char* p = ws + off;
        off = (off + nbytes + 255) & ~(size_t)255;
        return p;
    };
    unsigned short* W1T = (unsigned short*)take((size_t)ND * DHID * DIN * 2);
    unsigned short* W2T = (unsigned short*)take((size_t)ND * DOUT * DHID * 2);
    unsigned short* XS  = (unsigned short*)take((size_t)MPAD * DIN * 2);
    unsigned short* H   = (unsigned short*)take((size_t)MPAD * DHID * 2);
    float2* SPART = (float2*)take((size_t)8 * MPAD * 8);
    int* PERM   = (int*)take(MPAD * 4);
    int* POS    = (int*)take(NROWS * 4);
    int* CNT    = (int*)take(64);
    int2* META  = (int2*)take(NTILES * 8);
    (void)ws_size; (void)n_in; (void)in_sizes; (void)out_size;

    void* args[] = {
        (void*)&W1, (void*)&W1T, (void*)&W2, (void*)&W2T,
        (void*)&dt, (void*)&x, (void*)&XS, (void*)&PERM,
        (void*)&POS, (void*)&CNT, (void*)&META
    };
    hipLaunchCooperativeKernel((const void*)prep, dim3(PREPB), dim3(256),
                               args, 0, stream);

    gemm_a<<<NTILES * 8, 256, 0, stream>>>(XS, W1T, b1, META, H, SPART);
    gemm_b64<<<NTILES * 2, 256, 0, stream>>>(H, W2T, b2, META, PERM, out,
                                             SPART, gamma, beta);
}

// Round 8
// 212.973 us; speedup vs baseline: 4.9022x; 4.9022x over previous
//
#include <hip/hip_runtime.h>
#include <hip/hip_bf16.h>

// DomainEncoder: 8-expert MoE MLP, N=32768, 256 -> 1024 (LN+ReLU) -> 256.
// Round-8 vs round-7 (1044 us: cooperative grid.sync at 2048 blocks spins
// ~850 us on a cross-XCD atomic -- cooperative fusion abandoned):
//   - prep back to SEPARATE small kernels (round-5 structure, proven ~20 us):
//     transpose_both (now with W2T content pre-swizzle for gemm_b64),
//     init_histo, make_meta, assign_pos, copy_rows.
//   - gemm_a, gemm_b64 byte-identical to round-6/7 (correctness-validated):
//     gemm_b64 = BK=64 (16 steps, half the barriers) + T2 both-side swizzle.

#define ND 8
#define NROWS 32768
#define DIN 256
#define DHID 1024
#define DOUT 256
#define MPAD 33792          // 32768 + 8*128 worst-case padding
#define NTILES 264          // 256 + 8 worst-case row tiles (264 = 8*33)

typedef short short8 __attribute__((ext_vector_type(8)));
typedef float floatx4 __attribute__((ext_vector_type(4)));

__device__ __forceinline__ unsigned short f2bf(float f) {
    unsigned u = __builtin_bit_cast(unsigned, f);
    unsigned r = u + 0x7fff + ((u >> 16) & 1);   // RNE (inputs finite)
    return (unsigned short)(r >> 16);
}
__device__ __forceinline__ float bf2f(unsigned short h) {
    unsigned u = ((unsigned)h) << 16;
    return __builtin_bit_cast(float, u);
}

#define GLDS16(gp, lp) __builtin_amdgcn_global_load_lds( \
    (const __attribute__((address_space(1))) void*)(gp), \
    (__attribute__((address_space(3))) void*)(lp), 16, 0, 0)

// ---------------- 1. both weight transposes in one dispatch -------------------
// W1: fp32[8][256][1024] -> bf16[8][1024][256]
// W2: fp32[8][1024][256] -> bf16[8][256][1024], content PRE-swizzled:
//     k-slot bits [5:3] ^= row&7 (matches gemm_b64's LDS read XOR).
// Also zeroes CNT (stream-serialized before init_histo).
__global__ void transpose_both(const float* __restrict__ W1, unsigned short* __restrict__ W1T,
                               const float* __restrict__ W2, unsigned short* __restrict__ W2T,
                               int* __restrict__ cnt) {
    if (blockIdx.x == 0 && threadIdx.x < 16) cnt[threadIdx.x] = 0;
    __shared__ float t[32][33];
    int b = blockIdx.x;
    const float* in; unsigned short* out; int R, C, bx, by, z, is2;
    if (b < 2048) {           // W1: R=DIN, C=DHID
        in = W1; out = W1T; R = DIN; C = DHID; is2 = 0;
        bx = b & 31; by = (b >> 5) & 7; z = b >> 8;
    } else {                  // W2: R=DHID, C=DOUT
        b -= 2048;
        in = W2; out = W2T; R = DHID; C = DOUT; is2 = 1;
        bx = b & 7; by = (b >> 3) & 31; z = b >> 8;
    }
    const int c0 = bx * 32, r0 = by * 32;
    const int tx = threadIdx.x & 31, ty = threadIdx.x >> 5;   // 32x8
    const float* src = in + (size_t)z * R * C;
    unsigned short* dst = out + (size_t)z * R * C;
#pragma unroll
    for (int i = 0; i < 32; i += 8)
        t[ty + i][tx] = src[(size_t)(r0 + ty + i) * C + c0 + tx];
    __syncthreads();
#pragma unroll
    for (int i = 0; i < 32; i += 8) {
        const int row = c0 + ty + i;          // output row (N-dim)
        int k = r0 + tx;                      // output col (K-dim)
        if (is2)                              // content swizzle for BK=64 LDS
            k = (k & ~0x38) | (((((k >> 3) & 7) ^ (row & 7))) << 3);
        dst[(size_t)row * R + k] = f2bf(t[tx][ty + i]);
    }
}

// ---------------- 2a. perm init + histogram (merged) --------------------------
__global__ void init_histo(const int* __restrict__ dt, int* __restrict__ perm,
                           int* __restrict__ counts) {
    const int i = blockIdx.x * 256 + threadIdx.x;   // grid covers MPAD
    if (i < MPAD) perm[i] = -1;
    __shared__ int lc[ND];
    if (threadIdx.x < ND) lc[threadIdx.x] = 0;
    __syncthreads();
    if (i < NROWS) atomicAdd(&lc[dt[i]], 1);
    __syncthreads();
    if (threadIdx.x < ND && lc[threadIdx.x] > 0)
        atomicAdd(&counts[threadIdx.x], lc[threadIdx.x]);
}

// ---------------- 2b. aligned offsets + tile metadata (64 threads) ------------
__global__ void make_meta(const int* __restrict__ counts, int* __restrict__ cursors,
                          int2* __restrict__ meta) {
    __shared__ int base[ND], ntc[ND];
    const int t = threadIdx.x;
    if (t == 0) {
        int off = 0;
        for (int d = 0; d < ND; d++) {
            base[d] = off;
            ntc[d] = (counts[d] + 127) >> 7;
            cursors[d] = off;
            off += ntc[d] << 7;
        }
    }
    __syncthreads();
    for (int i = t; i < NTILES; i += 64) {
        int2 m = make_int2(-1, 0);
#pragma unroll
        for (int d = 0; d < ND; d++) {
            const int ti = i - (base[d] >> 7);
            if (ti >= 0 && ti < ntc[d]) m = make_int2(d, base[d] + (ti << 7));
        }
        meta[i] = m;
    }
}

// ---------------- 2c. position assignment: 8 global atomics per 256 rows ------
__global__ __launch_bounds__(256)
void assign_pos(const int* __restrict__ dt, int* __restrict__ cursors,
                int* __restrict__ perm, int* __restrict__ pos) {
    __shared__ int lcnt[ND];
    __shared__ int lbase[ND];
    const int tid = threadIdx.x;
    if (tid < ND) lcnt[tid] = 0;
    __syncthreads();
    const int r = blockIdx.x * 256 + tid;
    const int d = dt[r];
    const int myrank = atomicAdd(&lcnt[d], 1);   // LDS atomic: cheap
    __syncthreads();
    if (tid < ND && lcnt[tid] > 0)
        lbase[tid] = atomicAdd(&cursors[tid], lcnt[tid]);  // 8 global atomics/block
    __syncthreads();
    const int p = lbase[d] + myrank;
    pos[r] = p;
    perm[p] = r;
}

// ---------------- 2d. gather copy: one wave per row, coalesced ---------------
__global__ __launch_bounds__(256)
void copy_rows(const float* __restrict__ x, const int* __restrict__ pos,
               unsigned short* __restrict__ xs) {
    const int tid = threadIdx.x;
    const int lane = tid & 63;
    const int r = blockIdx.x * 4 + (tid >> 6);           // 4 rows per block
    const int p = pos[r];
    float4 v = ((const float4*)(x + (size_t)r * DIN))[lane];   // 16B/lane read
    ushort4 o;
    o.x = f2bf(v.x); o.y = f2bf(v.y); o.z = f2bf(v.z); o.w = f2bf(v.w);
    ((ushort4*)(xs + (size_t)p * DIN))[lane] = o;              // 8B/lane write
}

// ---------------- 3. GEMM-A: H = XS @ W1^T + b1, LN partials ------------------
// 128x128 tile, 4 waves 2x2, BK=32, dbuf single-barrier (round-5 structure).
__global__ __launch_bounds__(256, 2)
void gemm_a(const unsigned short* __restrict__ A,
            const unsigned short* __restrict__ Bt,
            const float* __restrict__ bias,
            const int2* __restrict__ meta,
            unsigned short* __restrict__ Cbf,
            float2* __restrict__ spart) {
    constexpr int K = DIN, Ntot = DHID, NB = 8, NWG = NTILES * NB, NS = K / 32;
    const int bid = (int)blockIdx.x;
    const int wid = (bid & 7) * (NWG >> 3) + (bid >> 3);
    const int tile = wid / NB;
    const int n0 = (wid % NB) * 128;
    const int2 md = meta[tile];
    const int dom = md.x;
    if (dom < 0) return;
    const int m0 = md.y;

    __shared__ unsigned short As[2][128 * 32];
    __shared__ unsigned short Bs[2][128 * 32];
    __shared__ float sred[2][128];

    const int tid = threadIdx.x;
    const int lane = tid & 63;
    const int w = tid >> 6;
    const int wr = w >> 1, wc = w & 1;
    const int l15 = lane & 15;

    const unsigned short* Abase = A + (size_t)m0 * K;
    const unsigned short* Bbase = Bt + (size_t)dom * Ntot * K + (size_t)n0 * K;

    if (tid < 128) { sred[0][tid] = 0.f; sred[1][tid] = 0.f; }

#define STAGE_AB(buf, t_) {                                                    \
        const int k0_ = (t_) * 32;                                             \
        _Pragma("unroll")                                                      \
        for (int it = 0; it < 2; ++it) {                                       \
            const int c = w * 128 + it * 64 + lane;                            \
            const int m_ = c >> 2, kcc = c & 3;                                \
            GLDS16(Bbase + (size_t)m_ * K + k0_ + kcc * 8,                     \
                   &Bs[buf][(w * 128 + it * 64) * 8]);                         \
            GLDS16(Abase + (size_t)m_ * K + k0_ + kcc * 8,                     \
                   &As[buf][(w * 128 + it * 64) * 8]);                         \
        }                                                                      \
    }

    floatx4 acc[4][4];
#pragma unroll
    for (int i = 0; i < 4; i++)
#pragma unroll
        for (int j = 0; j < 4; j++) acc[i][j] = 0.f;

    STAGE_AB(0, 0)
    __syncthreads();

    int cur = 0;
    const int kk = (lane >> 4) * 8;
    for (int t = 0; t < NS - 1; ++t) {
        const int nx = cur ^ 1;
        STAGE_AB(nx, t + 1)
        short8 a[4], b[4];
#pragma unroll
        for (int i = 0; i < 4; i++) {
            const int m = wr * 64 + i * 16 + l15;
            a[i] = *(const short8*)&As[cur][m * 32 + kk];
            const int n = wc * 64 + i * 16 + l15;
            b[i] = *(const short8*)&Bs[cur][n * 32 + kk];
        }
        __builtin_amdgcn_s_setprio(1);
#pragma unroll
        for (int i = 0; i < 4; i++)
#pragma unroll
            for (int j = 0; j < 4; j++)
                acc[i][j] = __builtin_amdgcn_mfma_f32_16x16x32_bf16(a[i], b[j], acc[i][j], 0, 0, 0);
        __builtin_amdgcn_s_setprio(0);
        __syncthreads();
        cur = nx;
    }
    {
        short8 a[4], b[4];
#pragma unroll
        for (int i = 0; i < 4; i++) {
            const int m = wr * 64 + i * 16 + l15;
            a[i] = *(const short8*)&As[cur][m * 32 + kk];
            const int n = wc * 64 + i * 16 + l15;
            b[i] = *(const short8*)&Bs[cur][n * 32 + kk];
        }
        __builtin_amdgcn_s_setprio(1);
#pragma unroll
        for (int i = 0; i < 4; i++)
#pragma unroll
            for (int j = 0; j < 4; j++)
                acc[i][j] = __builtin_amdgcn_mfma_f32_16x16x32_bf16(a[i], b[j], acc[i][j], 0, 0, 0);
        __builtin_amdgcn_s_setprio(0);
    }
#undef STAGE_AB

    // epilogue: write H = h+b1 (bf16) + per-row LN partials
    const int quad = lane >> 4;
    float bv[4];
#pragma unroll
    for (int j = 0; j < 4; j++)
        bv[j] = bias[dom * Ntot + n0 + wc * 64 + j * 16 + l15];
#pragma unroll
    for (int i = 0; i < 4; i++) {
#pragma unroll
        for (int r = 0; r < 4; r++) {
            const int rl = wr * 64 + i * 16 + quad * 4 + r;
            float s = 0.f, s2 = 0.f;
#pragma unroll
            for (int j = 0; j < 4; j++) {
                const float v = acc[i][j][r] + bv[j];
                Cbf[(size_t)(m0 + rl) * Ntot + n0 + wc * 64 + j * 16 + l15] = f2bf(v);
                s += v; s2 += v * v;
            }
#pragma unroll
            for (int o = 8; o; o >>= 1) {
                s  += __shfl_xor(s, o, 64);
                s2 += __shfl_xor(s2, o, 64);
            }
            if (l15 == 0) {
                atomicAdd(&sred[0][rl], s);
                atomicAdd(&sred[1][rl], s2);
            }
        }
    }
    __syncthreads();
    if (tid < 128)
        spart[(size_t)(n0 >> 7) * MPAD + m0 + tid] =
            make_float2(sred[0][tid], sred[1][tid]);
}

// ---------------- 4. GEMM-B: out = LN_ReLU(H) @ W2^T + b2, BK=64 --------------
// 128x128 tile, 4 waves 2x2, 16 K-steps, T2 XOR-swizzled LDS (A reg-staged,
// B linear GLDS from pre-swizzled W2T), scatter fp32 out via perm.
__global__ __launch_bounds__(256, 2)
void gemm_b64(const unsigned short* __restrict__ H,
              const unsigned short* __restrict__ W2T,
              const float* __restrict__ b2,
              const int2* __restrict__ meta,
              const int* __restrict__ perm,
              float* __restrict__ out,
              const float2* __restrict__ spart,
              const float* __restrict__ gamma,
              const float* __restrict__ beta) {
    constexpr int K = DHID, NWG = NTILES * 2, NS = K / 64;
    const int bid = (int)blockIdx.x;
    const int wid = (bid & 7) * (NWG >> 3) + (bid >> 3);
    const int tile = wid >> 1;
    const int n0 = (wid & 1) * 128;
    const int2 md = meta[tile];
    const int dom = md.x;
    if (dom < 0) return;
    const int m0 = md.y;

    __shared__ unsigned short As[2][128 * 64];   // 2 x 16 KB
    __shared__ unsigned short Bs[2][128 * 64];   // 2 x 16 KB
    __shared__ float gb[2048];                   // gamma[1024] beta[1024]

    const int tid = threadIdx.x;
    const int lane = tid & 63;
    const int w = tid >> 6;
    const int wr = w >> 1, wc = w & 1;
    const int l15 = lane & 15;
    const int quad = lane >> 4;

    const unsigned short* Hbase = H + (size_t)m0 * K;
    const unsigned short* Bbase = W2T + (size_t)dom * DOUT * K + (size_t)n0 * K;

    // gamma/beta -> LDS
    ((float4*)gb)[tid] = ((const float4*)(gamma + dom * DHID))[tid];
    ((float4*)(gb + 1024))[tid] = ((const float4*)(beta + dom * DHID))[tid];

    const int ma = w * 32 + (lane >> 2);   // staged rows: ma, ma+16
    const int kc = lane & 3;               // staged slots: kc, kc+4 (of 8)
    float muv[2], rsv[2];
#pragma unroll
    for (int h2 = 0; h2 < 2; ++h2) {
        const int rm = m0 + ma + h2 * 16;
        float s = 0.f, s2 = 0.f;
#pragma unroll
        for (int nb = 0; nb < 8; ++nb) {
            const float2 p = spart[(size_t)nb * MPAD + rm];
            s += p.x; s2 += p.y;
        }
        const float mu = s * (1.f / 1024.f);
        const float var = fmaxf(s2 * (1.f / 1024.f) - mu * mu, 0.f);
        muv[h2] = mu;
        rsv[h2] = rsqrtf(var + 1e-5f);
    }

    short8 hv[2][2];   // [row-half][slot-half], literal-indexed only

#define LOAD_H(t_) {                                                           \
        hv[0][0] = *(const short8*)(Hbase + (size_t)ma * K + (t_) * 64 + kc * 8);        \
        hv[0][1] = *(const short8*)(Hbase + (size_t)ma * K + (t_) * 64 + (kc + 4) * 8);  \
        hv[1][0] = *(const short8*)(Hbase + (size_t)(ma + 16) * K + (t_) * 64 + kc * 8); \
        hv[1][1] = *(const short8*)(Hbase + (size_t)(ma + 16) * K + (t_) * 64 + (kc + 4) * 8); }

#define XFRM(buf, t_) {                                                        \
        _Pragma("unroll")                                                      \
        for (int r2 = 0; r2 < 2; ++r2) {                                       \
            const int row = ma + r2 * 16;                                      \
            const float mu = muv[r2], rs = rsv[r2];                            \
            _Pragma("unroll")                                                  \
            for (int c2 = 0; c2 < 2; ++c2) {                                   \
                const int s_ = kc + c2 * 4;                                    \
                const int k1 = (t_) * 64 + s_ * 8;                             \
                const float4 g0 = *(const float4*)&gb[k1];                     \
                const float4 g1 = *(const float4*)&gb[k1 + 4];                 \
                const float4 e0 = *(const float4*)&gb[1024 + k1];              \
                const float4 e1 = *(const float4*)&gb[1024 + k1 + 4];          \
                const float gA[8] = {g0.x, g0.y, g0.z, g0.w,                   \
                                     g1.x, g1.y, g1.z, g1.w};                  \
                const float eA[8] = {e0.x, e0.y, e0.z, e0.w,                   \
                                     e1.x, e1.y, e1.z, e1.w};                  \
                const short8 hvv = hv[r2][c2];                                 \
                short8 o;                                                      \
                _Pragma("unroll")                                              \
                for (int e = 0; e < 8; ++e) {                                  \
                    const float rg = gA[e] * rs;                               \
                    const float v = fmaxf(fmaf(bf2f((unsigned short)hvv[e]),   \
                                   rg, fmaf(-mu, rg, eA[e])), 0.f);            \
                    o[e] = (short)f2bf(v);                                     \
                }                                                              \
                *(short8*)&As[buf][row * 64 + ((s_ ^ (row & 7)) << 3)] = o;    \
            }                                                                  \
        }                                                                      \
    }

#define STAGE_B(buf, t_) {                                                     \
        _Pragma("unroll")                                                      \
        for (int it = 0; it < 4; ++it) {                                       \
            const int cb = w * 256 + it * 64;                                  \
            const int c = cb + lane;                                           \
            const int m_ = c >> 3, j_ = c & 7;                                 \
            GLDS16(Bbase + (size_t)m_ * K + (t_) * 64 + j_ * 8,                \
                   &Bs[buf][cb * 8]);                                          \
        }                                                                      \
    }

#define COMPUTE(buf) {                                                         \
        _Pragma("unroll")                                                      \
        for (int h = 0; h < 2; ++h) {                                          \
            short8 a[4], b[4];                                                 \
            _Pragma("unroll")                                                  \
            for (int i = 0; i < 4; ++i) {                                      \
                const int m = wr * 64 + i * 16 + l15;                          \
                a[i] = *(const short8*)&As[buf][m * 64 +                       \
                        (((h * 4 + quad) ^ (m & 7)) << 3)];                    \
                const int n = wc * 64 + i * 16 + l15;                          \
                b[i] = *(const short8*)&Bs[buf][n * 64 +                       \
                        (((h * 4 + quad) ^ (n & 7)) << 3)];                    \
            }                                                                  \
            __builtin_amdgcn_s_setprio(1);                                     \
            _Pragma("unroll")                                                  \
            for (int i = 0; i < 4; ++i)                                        \
                _Pragma("unroll")                                              \
                for (int j = 0; j < 4; ++j)                                    \
                    acc[i][j] = __builtin_amdgcn_mfma_f32_16x16x32_bf16(       \
                        a[i], b[j], acc[i][j], 0, 0, 0);                       \
            __builtin_amdgcn_s_setprio(0);                                     \
        }                                                                      \
    }

    floatx4 acc[4][4];
#pragma unroll
    for (int i = 0; i < 4; i++)
#pragma unroll
        for (int j = 0; j < 4; j++) acc[i][j] = 0.f;

    // prologue
    STAGE_B(0, 0)          // fire-and-forget, earliest flight
    LOAD_H(0)
    __syncthreads();       // gb visible to all waves
    XFRM(0, 0)
    LOAD_H(1)
    __syncthreads();       // As[0] ds_writes + Bs[0] GLDS drained

    int cur = 0;
    for (int t = 0; t < NS - 1; ++t) {
        const int nx = cur ^ 1;
        STAGE_B(nx, t + 1)
        XFRM(nx, t + 1)                 // uses H(t+1) regs
        if (t + 2 < NS) LOAD_H(t + 2)   // flight = rest of this step
        COMPUTE(cur)
        __syncthreads();
        cur = nx;
    }
    COMPUTE(cur)

#undef LOAD_H
#undef XFRM
#undef STAGE_B
#undef COMPUTE

    // epilogue: scatter out = acc + b2 via perm (padding rows skipped)
    float bv[4];
#pragma unroll
    for (int j = 0; j < 4; j++)
        bv[j] = b2[dom * DOUT + n0 + wc * 64 + j * 16 + l15];
#pragma unroll
    for (int i = 0; i < 4; i++) {
        const int rowbase = m0 + wr * 64 + i * 16 + quad * 4;
#pragma unroll
        for (int r = 0; r < 4; r++) {
            const int orig = perm[rowbase + r];
            if (orig < 0) continue;
#pragma unroll
            for (int j = 0; j < 4; j++) {
                const int col = n0 + wc * 64 + j * 16 + l15;
                out[(size_t)orig * DOUT + col] = acc[i][j][r] + bv[j];
            }
        }
    }
}

// ---------------- launch ------------------------------------------------------
extern "C" void kernel_launch(void* const* d_in, const int* in_sizes, int n_in,
                              void* d_out, int out_size, void* d_ws, size_t ws_size,
                              hipStream_t stream) {
    const float* x = (const float*)d_in[0];
    const int* dt = (const int*)d_in[1];
    const float* W1 = (const float*)d_in[2];
    const float* b1 = (const float*)d_in[3];
    const float* gamma = (const float*)d_in[4];
    const float* beta = (const float*)d_in[5];
    const float* W2 = (const float*)d_in[6];
    const float* b2 = (const float*)d_in[7];
    float* out = (float*)d_out;

    char* ws = (char*)d_ws;
    size_t off = 0;
    auto take = [&](size_t nbytes) -> char* {
        char* p = ws + off;
        off = (off + nbytes + 255) & ~(size_t)255;
        return p;
    };
    unsigned short* W1T = (unsigned short*)take((size_t)ND * DHID * DIN * 2);
    unsigned short* W2T = (unsigned short*)take((size_t)ND * DOUT * DHID * 2);
    unsigned short* XS  = (unsigned short*)take((size_t)MPAD * DIN * 2);
    unsigned short* H   = (unsigned short*)take((size_t)MPAD * DHID * 2);
    float2* SPART = (float2*)take((size_t)8 * MPAD * 8);
    int* PERM   = (int*)take(MPAD * 4);
    int* POS    = (int*)take(NROWS * 4);
    int* CNT    = (int*)take(64);
    int2* META  = (int2*)take(NTILES * 8);
    (void)ws_size; (void)n_in; (void)in_sizes; (void)out_size;

    int* COUNTS = CNT;
    int* CURSORS = CNT + 8;

    transpose_both<<<4096, 256, 0, stream>>>(W1, W1T, W2, W2T, CNT);
    init_histo<<<(MPAD + 255) / 256, 256, 0, stream>>>(dt, PERM, COUNTS);
    make_meta<<<1, 64, 0, stream>>>(COUNTS, CURSORS, META);
    assign_pos<<<NROWS / 256, 256, 0, stream>>>(dt, CURSORS, PERM, POS);
    copy_rows<<<NROWS / 4, 256, 0, stream>>>(x, POS, XS);
    gemm_a<<<NTILES * 8, 256, 0, stream>>>(XS, W1T, b1, META, H, SPART);
    gemm_b64<<<NTILES * 2, 256, 0, stream>>>(H, W2T, b2, META, PERM, out,
                                             SPART, gamma, beta);
}